// Round 1
// baseline (6090.398 us; speedup 1.0000x reference)
//
#include <hip/hip_runtime.h>
#include <hip/hip_bf16.h>
#include <cstdint>

// ---------------------------------------------------------------------------
// InterModalityUpdate: B=16, NO=ML=512, VS=QS=OS=512, H=8, DH=64
// Round 0: correctness-first f32 baseline, bf16 intermediates in d_ws.
// ws layout (ushort elements):
//   vt : [8192][1536] v_trans bf16   (25.2 MB)
//   qt : [8192][1536] q_trans bf16   (25.2 MB)
//   vu : [8192][512]  v_update bf16  ( 8.4 MB)
//   qu : [8192][512]  q_update bf16  ( 8.4 MB)   total 64 MB
// ---------------------------------------------------------------------------

#define SEQ  512
#define N3   1536
#define MTOT 8192   // B*SEQ

__device__ __forceinline__ float blo(unsigned int u) { return __uint_as_float(u << 16); }
__device__ __forceinline__ float bhi(unsigned int u) { return __uint_as_float(u & 0xffff0000u); }
__device__ __forceinline__ unsigned short f2b(float f) {
  unsigned int u = __float_as_uint(f);
  unsigned int r = (u + 0x7fffu + ((u >> 16) & 1u)) >> 16;  // RNE
  return (unsigned short)r;
}

// -------- fused projection: out = (relu(in) @ W + bias) * mask, bf16 store --
__global__ __launch_bounds__(256) void proj_kernel(
    const float* __restrict__ in,      // [8192, 512]
    const float* __restrict__ W,       // [512, 1536]
    const float* __restrict__ bias,    // [1536]
    const float* __restrict__ mask,    // [8192]
    unsigned short* __restrict__ out)  // [8192, 1536] bf16
{
  __shared__ float As[16][68];  // [k][m]
  __shared__ float Bs[16][68];  // [k][n]
  const int tx = threadIdx.x & 15, ty = threadIdx.x >> 4;
  const int n0 = blockIdx.x * 64, m0 = blockIdx.y * 64;
  float acc[4][4] = {};
  for (int k0 = 0; k0 < 512; k0 += 16) {
    {
      const int row = threadIdx.x >> 2, kq = (threadIdx.x & 3) << 2;
      float4 a4 = *reinterpret_cast<const float4*>(&in[(size_t)(m0 + row) * 512 + k0 + kq]);
      As[kq + 0][row] = fmaxf(a4.x, 0.f);
      As[kq + 1][row] = fmaxf(a4.y, 0.f);
      As[kq + 2][row] = fmaxf(a4.z, 0.f);
      As[kq + 3][row] = fmaxf(a4.w, 0.f);
    }
#pragma unroll
    for (int i = 0; i < 4; ++i) {
      int idx = threadIdx.x + (i << 8);
      int kk = idx >> 6, nn = idx & 63;
      Bs[kk][nn] = W[(size_t)(k0 + kk) * N3 + n0 + nn];
    }
    __syncthreads();
#pragma unroll
    for (int k = 0; k < 16; ++k) {
      float4 a = *reinterpret_cast<const float4*>(&As[k][ty << 2]);
      float4 b = *reinterpret_cast<const float4*>(&Bs[k][tx << 2]);
      float av[4] = {a.x, a.y, a.z, a.w};
      float bw[4] = {b.x, b.y, b.z, b.w};
#pragma unroll
      for (int i = 0; i < 4; ++i)
#pragma unroll
        for (int j = 0; j < 4; ++j)
          acc[i][j] = fmaf(av[i], bw[j], acc[i][j]);
    }
    __syncthreads();
  }
#pragma unroll
  for (int i = 0; i < 4; ++i) {
    const int gm = m0 + (ty << 2) + i;
    const float mk = mask[gm];
#pragma unroll
    for (int j = 0; j < 4; ++j) {
      const int gn = n0 + (tx << 2) + j;
      out[(size_t)gm * N3 + gn] = f2b((acc[i][j] + bias[gn]) * mk);
    }
  }
}

// -------- output projection: out = concat(x, upd) @ W + bias (f32 out) -----
__global__ __launch_bounds__(256) void outproj_kernel(
    const float* __restrict__ x,          // [8192, 512] original input
    const unsigned short* __restrict__ upd, // [8192, 512] bf16 update
    const float* __restrict__ W,          // [1024, 512]
    const float* __restrict__ bias,       // [512]
    float* __restrict__ out)              // [8192, 512]
{
  __shared__ float As[16][68];
  __shared__ float Bs[16][68];
  const int tx = threadIdx.x & 15, ty = threadIdx.x >> 4;
  const int n0 = blockIdx.x * 64, m0 = blockIdx.y * 64;
  float acc[4][4] = {};
  for (int k0 = 0; k0 < 1024; k0 += 16) {
    {
      const int row = threadIdx.x >> 2, kq = (threadIdx.x & 3) << 2;
      if (k0 < 512) {
        float4 a4 = *reinterpret_cast<const float4*>(&x[(size_t)(m0 + row) * 512 + k0 + kq]);
        As[kq + 0][row] = a4.x;
        As[kq + 1][row] = a4.y;
        As[kq + 2][row] = a4.z;
        As[kq + 3][row] = a4.w;
      } else {
        uint2 u = *reinterpret_cast<const uint2*>(&upd[(size_t)(m0 + row) * 512 + (k0 - 512) + kq]);
        As[kq + 0][row] = blo(u.x);
        As[kq + 1][row] = bhi(u.x);
        As[kq + 2][row] = blo(u.y);
        As[kq + 3][row] = bhi(u.y);
      }
    }
#pragma unroll
    for (int i = 0; i < 4; ++i) {
      int idx = threadIdx.x + (i << 8);
      int kk = idx >> 6, nn = idx & 63;
      Bs[kk][nn] = W[(size_t)(k0 + kk) * 512 + n0 + nn];
    }
    __syncthreads();
#pragma unroll
    for (int k = 0; k < 16; ++k) {
      float4 a = *reinterpret_cast<const float4*>(&As[k][ty << 2]);
      float4 b = *reinterpret_cast<const float4*>(&Bs[k][tx << 2]);
      float av[4] = {a.x, a.y, a.z, a.w};
      float bw[4] = {b.x, b.y, b.z, b.w};
#pragma unroll
      for (int i = 0; i < 4; ++i)
#pragma unroll
        for (int j = 0; j < 4; ++j)
          acc[i][j] = fmaf(av[i], bw[j], acc[i][j]);
    }
    __syncthreads();
  }
#pragma unroll
  for (int i = 0; i < 4; ++i) {
    const int gm = m0 + (ty << 2) + i;
#pragma unroll
    for (int j = 0; j < 4; ++j) {
      const int gn = n0 + (tx << 2) + j;
      out[(size_t)gm * 512 + gn] = acc[i][j] + bias[gn];
    }
  }
}

// -------- cross attention -------------------------------------------------
// Q rows from Qt (cols 512+h*64..), K from KVt (cols h*64..), V from KVt
// (cols 1024+h*64..). score = (mask? q.k : -1e9)/8, softmax over kv, out=P@V.
__global__ __launch_bounds__(512) void attn_kernel(
    const unsigned short* __restrict__ Qt,   // [8192,1536] bf16
    const unsigned short* __restrict__ KVt,  // [8192,1536] bf16
    const float* __restrict__ mask,          // [8192] kv-side mask
    unsigned short* __restrict__ outu)       // [8192,512] bf16 update
{
  __shared__ uint2 Kq[16][513];        // k4-major packed (4 bf16/entry), 65.7KB
  __shared__ unsigned int Vp[512][32]; // m-major packed d-pairs, 64KB
  __shared__ float pb[8][512];         // per-wave probabilities, 16KB
  __shared__ float mbuf[512];          // kv mask, 2KB
  const int b = blockIdx.z, h = blockIdx.y;
  const int n0 = blockIdx.x * 128;
  const int t = threadIdx.x, w = t >> 6, lane = t & 63;
  const size_t rowbase = (size_t)b * 512;

  // stage K: [512 m][16 uint2]
#pragma unroll
  for (int i = 0; i < 16; ++i) {
    int idx = t + (i << 9);
    int m = idx >> 4, k4 = idx & 15;
    const uint2* src = reinterpret_cast<const uint2*>(KVt + (rowbase + m) * N3 + h * 64);
    Kq[k4][m] = src[k4];
  }
  // stage V: [512 m][32 uint]
#pragma unroll
  for (int i = 0; i < 32; ++i) {
    int idx = t + (i << 9);
    int m = idx >> 5, d2 = idx & 31;
    const unsigned int* src = reinterpret_cast<const unsigned int*>(KVt + (rowbase + m) * N3 + 1024 + h * 64);
    Vp[m][d2] = src[d2];
  }
  mbuf[t & 511] = mask[rowbase + (t & 511)];
  __syncthreads();

  const int myrow0 = n0 + w * 16;
  for (int it = 0; it < 16; ++it) {
    const int n = myrow0 + it;
    // q row (64 bf16 = 32 uints), replicated across half-waves
    const unsigned int qp =
        reinterpret_cast<const unsigned int*>(Qt + (rowbase + n) * N3 + 512 + h * 64)[lane & 31];
    float s[8] = {0.f, 0.f, 0.f, 0.f, 0.f, 0.f, 0.f, 0.f};
#pragma unroll
    for (int k4 = 0; k4 < 16; ++k4) {
      unsigned int uq0 = __shfl(qp, 2 * k4);
      unsigned int uq1 = __shfl(qp, 2 * k4 + 1);
      float q0 = blo(uq0), q1 = bhi(uq0), q2 = blo(uq1), q3 = bhi(uq1);
#pragma unroll
      for (int j = 0; j < 8; ++j) {
        uint2 uk = Kq[k4][lane + 64 * j];
        s[j] = fmaf(blo(uk.x), q0, s[j]);
        s[j] = fmaf(bhi(uk.x), q1, s[j]);
        s[j] = fmaf(blo(uk.y), q2, s[j]);
        s[j] = fmaf(bhi(uk.y), q3, s[j]);
      }
    }
    // mask, scale, softmax over 512 (distributed m = lane + 64j)
    float mx = -3.4e38f;
#pragma unroll
    for (int j = 0; j < 8; ++j) {
      float mk = mbuf[lane + 64 * j];
      s[j] = (mk == 0.f) ? -1e9f : s[j];
      s[j] *= 0.125f;
      mx = fmaxf(mx, s[j]);
    }
#pragma unroll
    for (int off = 32; off; off >>= 1) mx = fmaxf(mx, __shfl_xor(mx, off));
    float sum = 0.f;
#pragma unroll
    for (int j = 0; j < 8; ++j) { s[j] = __expf(s[j] - mx); sum += s[j]; }
#pragma unroll
    for (int off = 32; off; off >>= 1) sum += __shfl_xor(sum, off);
    const float inv = 1.f / sum;
#pragma unroll
    for (int j = 0; j < 8; ++j) pb[w][lane + 64 * j] = s[j] * inv;
    // PV: lanes 0..31 take m in [0,256), lanes 32..63 take [256,512); d2 = lane&31
    const int d2 = lane & 31, half = lane >> 5;
    float o0 = 0.f, o1 = 0.f;
#pragma unroll 8
    for (int mi = 0; mi < 256; ++mi) {
      int m = half * 256 + mi;
      float p = pb[w][m];
      unsigned int uv = Vp[m][d2];
      o0 = fmaf(blo(uv), p, o0);
      o1 = fmaf(bhi(uv), p, o1);
    }
    o0 += __shfl_xor(o0, 32);
    o1 += __shfl_xor(o1, 32);
    if (lane < 32) {
      unsigned int pk = ((unsigned int)f2b(o1) << 16) | (unsigned int)f2b(o0);
      reinterpret_cast<unsigned int*>(outu + (rowbase + n) * 512 + h * 64)[d2] = pk;
    }
  }
}

// ---------------------------------------------------------------------------
extern "C" void kernel_launch(void* const* d_in, const int* in_sizes, int n_in,
                              void* d_out, int out_size, void* d_ws, size_t ws_size,
                              hipStream_t stream) {
  const float* v      = (const float*)d_in[0];
  const float* q      = (const float*)d_in[1];
  const float* v_mask = (const float*)d_in[2];
  const float* q_mask = (const float*)d_in[3];
  const float* Wv     = (const float*)d_in[4];
  const float* bv     = (const float*)d_in[5];
  const float* Wq     = (const float*)d_in[6];
  const float* bq     = (const float*)d_in[7];
  const float* Wvo    = (const float*)d_in[8];
  const float* bvo    = (const float*)d_in[9];
  const float* Wqo    = (const float*)d_in[10];
  const float* bqo    = (const float*)d_in[11];
  float* out_v = (float*)d_out;
  float* out_q = out_v + (size_t)MTOT * 512;

  unsigned short* vt = (unsigned short*)d_ws;
  unsigned short* qt = vt + (size_t)MTOT * N3;
  unsigned short* vu = qt + (size_t)MTOT * N3;
  unsigned short* qu = vu + (size_t)MTOT * 512;

  proj_kernel<<<dim3(24, 128), 256, 0, stream>>>(v, Wv, bv, v_mask, vt);
  proj_kernel<<<dim3(24, 128), 256, 0, stream>>>(q, Wq, bq, q_mask, qt);
  // q->v attention: queries = v_q, keys = q_k, values = q_v, mask = q_mask
  attn_kernel<<<dim3(4, 8, 16), 512, 0, stream>>>(vt, qt, q_mask, vu);
  // v->q attention: queries = q_q, keys = v_k, values = v_v, mask = v_mask
  attn_kernel<<<dim3(4, 8, 16), 512, 0, stream>>>(qt, vt, v_mask, qu);
  outproj_kernel<<<dim3(8, 128), 256, 0, stream>>>(v, vu, Wvo, bvo, out_v);
  outproj_kernel<<<dim3(8, 128), 256, 0, stream>>>(q, qu, Wqo, bqo, out_q);
}

// Round 2
// 403.338 us; speedup vs baseline: 15.1000x; 15.1000x over previous
//
#include <hip/hip_runtime.h>
#include <cstdint>

// ---------------------------------------------------------------------------
// InterModalityUpdate R1: all-MFMA bf16 pipeline.
// B=16, NO=ML=512, VS=QS=OS=512, H=8, DH=64.
//
// ws layout (ushort): vt[8192*1536], qt[8192*1536], qu[8192*512],
//                     WvT[1536*512], WqT[1536*512], WvoT[512*1024], WqoT[512*1024]
//                     = 63,963,136 B  (<= 64 MiB proven available)
// vu lives in d_out's out_q half (dead by the time outproj_q writes it).
// ---------------------------------------------------------------------------

#define N3 1536
#define MTOT 8192

typedef __attribute__((ext_vector_type(8))) short short8;
typedef __attribute__((ext_vector_type(4))) float f32x4;
typedef unsigned short u16;
typedef unsigned int u32;

static __device__ __forceinline__ u16 f2b(float f) {
  u32 u = __float_as_uint(f);
  return (u16)((u + 0x7fffu + ((u >> 16) & 1u)) >> 16);  // RNE
}
static __device__ __forceinline__ u32 pack2(float lo, float hi) {
  return (u32)f2b(lo) | ((u32)f2b(hi) << 16);
}

// -------- weight transpose + bf16 convert: W[R][C] f32 -> Wt[C][R] bf16 ----
__global__ __launch_bounds__(256) void wtrans(
    const float* __restrict__ W, u16* __restrict__ Wt, int R, int C) {
  __shared__ float tile[32][33];
  const int tx = threadIdx.x & 31, ty = threadIdx.x >> 5;
  const int c0 = blockIdx.x * 32, r0 = blockIdx.y * 32;
#pragma unroll
  for (int i = 0; i < 4; ++i)
    tile[ty + i * 8][tx] = W[(size_t)(r0 + ty + i * 8) * C + c0 + tx];
  __syncthreads();
#pragma unroll
  for (int i = 0; i < 4; ++i) {
    int c = c0 + ty + i * 8;
    Wt[(size_t)c * R + r0 + tx] = f2b(tile[tx][ty + i * 8]);
  }
}

// -------- proj: out_bf16[8192][1536] = (relu(A_f32) @ W + bias) * mask -----
// Bt is W^T bf16 [1536][512]. Tile 128x128, Kstep=64, 4 waves (2x2).
__global__ __launch_bounds__(256) void proj_mfma(
    const float* __restrict__ A, const u16* __restrict__ Bt,
    const float* __restrict__ bias, const float* __restrict__ mask,
    u16* __restrict__ out) {
  __shared__ u16 Asm[128][72];  // +8 pad: 144B rows, 2-way banks
  __shared__ u16 Bsm[128][72];
  const int t = threadIdx.x, l = t & 63, w = t >> 6;
  const int lx = l & 15, g = l >> 4;
  const int wr = w >> 1, wc = w & 1;
  const int m0 = blockIdx.y * 128, n0 = blockIdx.x * 128;
  f32x4 acc[4][4];
#pragma unroll
  for (int i = 0; i < 4; ++i)
#pragma unroll
    for (int j = 0; j < 4; ++j) acc[i][j] = (f32x4){0.f, 0.f, 0.f, 0.f};

  for (int k0 = 0; k0 < 512; k0 += 64) {
#pragma unroll
    for (int i = 0; i < 4; ++i) {
      int idx = t + i * 256;  // 0..1023 -> (row 0..127, k-octet 0..7)
      int row = idx >> 3, k8 = idx & 7;
      const float* src = &A[(size_t)(m0 + row) * 512 + k0 + k8 * 8];
      float4 a = *(const float4*)src;
      float4 b = *(const float4*)(src + 4);
      uint4 aw = make_uint4(pack2(fmaxf(a.x, 0.f), fmaxf(a.y, 0.f)),
                            pack2(fmaxf(a.z, 0.f), fmaxf(a.w, 0.f)),
                            pack2(fmaxf(b.x, 0.f), fmaxf(b.y, 0.f)),
                            pack2(fmaxf(b.z, 0.f), fmaxf(b.w, 0.f)));
      *(uint4*)&Asm[row][k8 * 8] = aw;
      *(uint4*)&Bsm[row][k8 * 8] =
          *(const uint4*)&Bt[(size_t)(n0 + row) * 512 + k0 + k8 * 8];
    }
    __syncthreads();
#pragma unroll
    for (int kc = 0; kc < 2; ++kc) {
      short8 am[4], bn[4];
#pragma unroll
      for (int mt = 0; mt < 4; ++mt)
        am[mt] = *(const short8*)&Asm[wr * 64 + mt * 16 + lx][kc * 32 + g * 8];
#pragma unroll
      for (int nt = 0; nt < 4; ++nt)
        bn[nt] = *(const short8*)&Bsm[wc * 64 + nt * 16 + lx][kc * 32 + g * 8];
#pragma unroll
      for (int mt = 0; mt < 4; ++mt)
#pragma unroll
        for (int nt = 0; nt < 4; ++nt)
          acc[mt][nt] = __builtin_amdgcn_mfma_f32_16x16x32_bf16(
              am[mt], bn[nt], acc[mt][nt], 0, 0, 0);
    }
    __syncthreads();
  }
#pragma unroll
  for (int nt = 0; nt < 4; ++nt) {
    const int n = n0 + wc * 64 + nt * 16 + lx;
    const float bs = bias[n];
#pragma unroll
    for (int mt = 0; mt < 4; ++mt)
#pragma unroll
      for (int r = 0; r < 4; ++r) {
        int m = m0 + wr * 64 + mt * 16 + g * 4 + r;
        out[(size_t)m * N3 + n] = f2b((acc[mt][nt][r] + bs) * mask[m]);
      }
  }
}

// -------- outproj: out_f32[8192][512] = concat(X_f32, U_bf16) @ W + bias ---
// Bt is W^T bf16 [512][1024]. K=1024 (k<512 from X, else U).
__global__ __launch_bounds__(256) void outproj_mfma(
    const float* __restrict__ X, const u16* __restrict__ U,
    const u16* __restrict__ Bt, const float* __restrict__ bias,
    float* __restrict__ out) {
  __shared__ u16 Asm[128][72];
  __shared__ u16 Bsm[128][72];
  const int t = threadIdx.x, l = t & 63, w = t >> 6;
  const int lx = l & 15, g = l >> 4;
  const int wr = w >> 1, wc = w & 1;
  const int m0 = blockIdx.y * 128, n0 = blockIdx.x * 128;
  f32x4 acc[4][4];
#pragma unroll
  for (int i = 0; i < 4; ++i)
#pragma unroll
    for (int j = 0; j < 4; ++j) acc[i][j] = (f32x4){0.f, 0.f, 0.f, 0.f};

  for (int k0 = 0; k0 < 1024; k0 += 64) {
#pragma unroll
    for (int i = 0; i < 4; ++i) {
      int idx = t + i * 256;
      int row = idx >> 3, k8 = idx & 7;
      uint4 aw;
      if (k0 < 512) {
        const float* src = &X[(size_t)(m0 + row) * 512 + k0 + k8 * 8];
        float4 a = *(const float4*)src;
        float4 b = *(const float4*)(src + 4);
        aw = make_uint4(pack2(a.x, a.y), pack2(a.z, a.w), pack2(b.x, b.y),
                        pack2(b.z, b.w));
      } else {
        aw = *(const uint4*)&U[(size_t)(m0 + row) * 512 + (k0 - 512) + k8 * 8];
      }
      *(uint4*)&Asm[row][k8 * 8] = aw;
      *(uint4*)&Bsm[row][k8 * 8] =
          *(const uint4*)&Bt[(size_t)(n0 + row) * 1024 + k0 + k8 * 8];
    }
    __syncthreads();
#pragma unroll
    for (int kc = 0; kc < 2; ++kc) {
      short8 am[4], bn[4];
#pragma unroll
      for (int mt = 0; mt < 4; ++mt)
        am[mt] = *(const short8*)&Asm[wr * 64 + mt * 16 + lx][kc * 32 + g * 8];
#pragma unroll
      for (int nt = 0; nt < 4; ++nt)
        bn[nt] = *(const short8*)&Bsm[wc * 64 + nt * 16 + lx][kc * 32 + g * 8];
#pragma unroll
      for (int mt = 0; mt < 4; ++mt)
#pragma unroll
        for (int nt = 0; nt < 4; ++nt)
          acc[mt][nt] = __builtin_amdgcn_mfma_f32_16x16x32_bf16(
              am[mt], bn[nt], acc[mt][nt], 0, 0, 0);
    }
    __syncthreads();
  }
#pragma unroll
  for (int nt = 0; nt < 4; ++nt) {
    const int n = n0 + wc * 64 + nt * 16 + lx;
    const float bs = bias[n];
#pragma unroll
    for (int mt = 0; mt < 4; ++mt)
#pragma unroll
      for (int r = 0; r < 4; ++r) {
        int m = m0 + wr * 64 + mt * 16 + g * 4 + r;
        out[(size_t)m * 512 + n] = acc[mt][nt][r] + bs;
      }
  }
}

// -------- attention: swapped QK^T (S^T = K*Q^T), lane-local softmax, PV ----
// Q rows: Qt cols 512+h*64; K: KVt cols h*64; V: KVt cols 1024+h*64.
// Block: 512 thr = 8 waves, each wave 16 q-rows; grid (4, 8, 16).
__global__ __launch_bounds__(512) void attn_mfma(
    const u16* __restrict__ Qt, const u16* __restrict__ KVt,
    const float* __restrict__ mask, u16* __restrict__ outu) {
  __shared__ u16 Vt[64][520];      // V^T, +8 pad (1040B rows, 2-way banks)
  __shared__ u16 Plds[8][16][40];  // per-wave P chunk [16q][32kv+8pad]
  __shared__ float mbuf[512];
  const int b = blockIdx.z, h = blockIdx.y;
  const int qt0 = blockIdx.x * 128;
  const int t = threadIdx.x, w = t >> 6, l = t & 63;
  const int lx = l & 15, g = l >> 4;
  const size_t rowbase = (size_t)b * 512;

  // ---- stage V^T (pack kv-pairs into u32 along kv) ----
#pragma unroll
  for (int it = 0; it < 4; ++it) {
    int idx = t + it * 512;  // 0..2047: (kv-pair 0..255, d-octet 0..7)
    int kvp = idx & 255, d8 = (idx >> 8) * 8;
    const u16* s0 = &KVt[(rowbase + 2 * kvp) * N3 + 1024 + h * 64 + d8];
    uint4 r0 = *(const uint4*)s0;
    uint4 r1 = *(const uint4*)(s0 + N3);
    u32 rw0[4] = {r0.x, r0.y, r0.z, r0.w};
    u32 rw1[4] = {r1.x, r1.y, r1.z, r1.w};
#pragma unroll
    for (int jj = 0; jj < 4; ++jj) {
      u32 lo = (rw0[jj] & 0xffffu) | (rw1[jj] << 16);
      u32 hi = (rw0[jj] >> 16) | (rw1[jj] & 0xffff0000u);
      *(u32*)&Vt[d8 + 2 * jj][2 * kvp] = lo;
      *(u32*)&Vt[d8 + 2 * jj + 1][2 * kvp] = hi;
    }
  }
  mbuf[t & 511] = mask[rowbase + (t & 511)];
  __syncthreads();

  // ---- Q fragments (B-operand: n=q=lx, k=d) ----
  const int qrow = qt0 + w * 16 + lx;
  const u16* qp = &Qt[(rowbase + qrow) * N3 + 512 + h * 64 + g * 8];
  const short8 qf0 = *(const short8*)qp;
  const short8 qf1 = *(const short8*)(qp + 32);

  // ---- S^T = K @ Q^T : sacc[kt] holds S^T[kv=kt*16+g*4+r][q=lx] ----
  f32x4 sacc[32];
#pragma unroll
  for (int i = 0; i < 32; ++i) sacc[i] = (f32x4){0.f, 0.f, 0.f, 0.f};
#pragma unroll
  for (int kt = 0; kt < 32; ++kt) {
    const u16* kp = &KVt[(rowbase + kt * 16 + lx) * N3 + h * 64 + g * 8];
    short8 kf0 = *(const short8*)kp;
    short8 kf1 = *(const short8*)(kp + 32);
    sacc[kt] = __builtin_amdgcn_mfma_f32_16x16x32_bf16(kf0, qf0, sacc[kt], 0, 0, 0);
    sacc[kt] = __builtin_amdgcn_mfma_f32_16x16x32_bf16(kf1, qf1, sacc[kt], 0, 0, 0);
  }

  // ---- mask (pre-scale, like ref), scale, row max (lane-local + 2 shfl) ----
  const float4* mb4 = (const float4*)mbuf;
  float mx = -3.4e38f;
#pragma unroll
  for (int kt = 0; kt < 32; ++kt) {
    float4 mk = mb4[kt * 4 + g];
    float mv[4] = {mk.x, mk.y, mk.z, mk.w};
#pragma unroll
    for (int r = 0; r < 4; ++r) {
      float sv = sacc[kt][r];
      sv = (mv[r] == 0.f) ? -1e9f : sv;
      sv *= 0.125f;
      sacc[kt][r] = sv;
      mx = fmaxf(mx, sv);
    }
  }
  mx = fmaxf(mx, __shfl_xor(mx, 16));
  mx = fmaxf(mx, __shfl_xor(mx, 32));

  // ---- exp -> P(bf16, unnormalized) -> PV MFMA; sum alongside ----
  f32x4 oacc[4];
#pragma unroll
  for (int i = 0; i < 4; ++i) oacc[i] = (f32x4){0.f, 0.f, 0.f, 0.f};
  float sum = 0.f;
#pragma unroll
  for (int c8 = 0; c8 < 16; ++c8) {
#pragma unroll
    for (int u = 0; u < 2; ++u) {
      int kt = c8 * 2 + u;
      float e0 = __expf(sacc[kt][0] - mx);
      float e1 = __expf(sacc[kt][1] - mx);
      float e2 = __expf(sacc[kt][2] - mx);
      float e3 = __expf(sacc[kt][3] - mx);
      sum += (e0 + e1) + (e2 + e3);
      *(uint2*)&Plds[w][lx][u * 16 + g * 4] =
          make_uint2(pack2(e0, e1), pack2(e2, e3));
    }
    short8 pa = *(const short8*)&Plds[w][lx][g * 8];
#pragma unroll
    for (int nt = 0; nt < 4; ++nt) {
      short8 bv = *(const short8*)&Vt[nt * 16 + lx][c8 * 32 + g * 8];
      oacc[nt] = __builtin_amdgcn_mfma_f32_16x16x32_bf16(pa, bv, oacc[nt], 0, 0, 0);
    }
  }
  sum += __shfl_xor(sum, 16);
  sum += __shfl_xor(sum, 32);
  const float inv = 1.f / sum;
  float invr[4];
#pragma unroll
  for (int r = 0; r < 4; ++r) invr[r] = __shfl(inv, g * 4 + r);

  // ---- epilogue: O[q][d], q=(g*4+r), d=nt*16+lx ----
#pragma unroll
  for (int r = 0; r < 4; ++r) {
    int qr = qt0 + w * 16 + g * 4 + r;
    u16* op = &outu[(rowbase + qr) * 512 + h * 64 + lx];
#pragma unroll
    for (int nt = 0; nt < 4; ++nt) op[nt * 16] = f2b(oacc[nt][r] * invr[r]);
  }
}

// ---------------------------------------------------------------------------
extern "C" void kernel_launch(void* const* d_in, const int* in_sizes, int n_in,
                              void* d_out, int out_size, void* d_ws, size_t ws_size,
                              hipStream_t stream) {
  const float* v      = (const float*)d_in[0];
  const float* q      = (const float*)d_in[1];
  const float* v_mask = (const float*)d_in[2];
  const float* q_mask = (const float*)d_in[3];
  const float* Wv     = (const float*)d_in[4];
  const float* bv     = (const float*)d_in[5];
  const float* Wq     = (const float*)d_in[6];
  const float* bq     = (const float*)d_in[7];
  const float* Wvo    = (const float*)d_in[8];
  const float* bvo    = (const float*)d_in[9];
  const float* Wqo    = (const float*)d_in[10];
  const float* bqo    = (const float*)d_in[11];
  float* out_v = (float*)d_out;
  float* out_q = out_v + (size_t)MTOT * 512;

  u16* vt   = (u16*)d_ws;                       // [8192][1536]
  u16* qt   = vt + (size_t)MTOT * N3;           // [8192][1536]
  u16* qu   = qt + (size_t)MTOT * N3;           // [8192][512]
  u16* WvT  = qu + (size_t)MTOT * 512;          // [1536][512]
  u16* WqT  = WvT + (size_t)N3 * 512;           // [1536][512]
  u16* WvoT = WqT + (size_t)N3 * 512;           // [512][1024]
  u16* WqoT = WvoT + (size_t)512 * 1024;        // [512][1024]
  u16* vu   = (u16*)(out_q);                    // [8192][512] in out_q space

  wtrans<<<dim3(48, 16), 256, 0, stream>>>(Wv, WvT, 512, 1536);
  wtrans<<<dim3(48, 16), 256, 0, stream>>>(Wq, WqT, 512, 1536);
  wtrans<<<dim3(16, 32), 256, 0, stream>>>(Wvo, WvoT, 1024, 512);
  wtrans<<<dim3(16, 32), 256, 0, stream>>>(Wqo, WqoT, 1024, 512);

  proj_mfma<<<dim3(12, 64), 256, 0, stream>>>(v, WvT, bv, v_mask, vt);
  proj_mfma<<<dim3(12, 64), 256, 0, stream>>>(q, WqT, bq, q_mask, qt);

  // q->v attention: queries from vt, K/V from qt, kv mask = q_mask
  attn_mfma<<<dim3(4, 8, 16), 512, 0, stream>>>(vt, qt, q_mask, vu);
  // v->q attention: queries from qt, K/V from vt, kv mask = v_mask
  attn_mfma<<<dim3(4, 8, 16), 512, 0, stream>>>(qt, vt, v_mask, qu);

  outproj_mfma<<<dim3(4, 64), 256, 0, stream>>>(v, vu, WvoT, bvo, out_v);
  outproj_mfma<<<dim3(4, 64), 256, 0, stream>>>(q, qu, WqoT, bqo, out_q);
}